// Round 6
// baseline (5804.834 us; speedup 1.0000x reference)
//
#include <hip/hip_runtime.h>

// LSTMPricePredictor: B=4096, T=512, IN=1, H=50, 2 layers + FC(50->1)
// R6: PIN the weights in VGPRs with an opaque asm pass-through.
//   R1-R5 post-mortem: the compiler re-streamed each thread's 80 weight
//   floats from L1 every timestep (VGPR_Count 76-128 across 5 variants,
//   dur pinned at ~4.5 ms = L1-BW/issue bound on weight refetch; FETCH
//   tiny because it's all cache hits). Pressure tricks (R2-R4) and
//   may-alias stores (R5) both failed because the loads remain visible.
//   Fix: asm volatile("" : "+v"(w)) makes each loaded weight an OPAQUE
//   value -- rematerialization is impossible, the 80 floats must stay
//   live in VGPRs for all 512 iterations. __launch_bounds__(512,4) caps
//   VGPRs at 128 so 2 blocks/CU still fit. Explicit fmaf() guarantees
//   contraction.
// Structure = R4 (passed, absmax 0): 512 blocks x 512 threads, TB=8 rows,
//   wave = (gate-quarter q, k-half m); partial gate sums via LDS.

#define T_STEPS 512
#define HID 50
#define TB 8          // batch rows per block
#define P0 56         // h0 row pitch (14 float4; halves of 7 float4)
#define P1 104        // [h0_t ; h1_{t-1}] pitch (halves of 13 float4)
#define GP 200        // gates row pitch

__device__ __forceinline__ float sigm(float x) {
    return 1.0f / (1.0f + __expf(-x));
}
__device__ __forceinline__ float tanhh(float x) {
    return 1.0f - 2.0f / (1.0f + __expf(2.0f * x));
}

#define L7(F)  F(0) F(1) F(2) F(3) F(4) F(5) F(6)
#define L13(F) F(0) F(1) F(2) F(3) F(4) F(5) F(6) F(7) F(8) F(9) F(10) F(11) F(12)

extern "C" __global__ __launch_bounds__(512, 4)
void lstm2_fc_kernel(const float* __restrict__ x,
                     const float* __restrict__ W_ih0, const float* __restrict__ W_hh0,
                     const float* __restrict__ b_ih0, const float* __restrict__ b_hh0,
                     const float* __restrict__ W_ih1, const float* __restrict__ W_hh1,
                     const float* __restrict__ b_ih1, const float* __restrict__ b_hh1,
                     const float* __restrict__ fc_w, const float* __restrict__ fc_b,
                     float* __restrict__ out)
{
    __shared__ float xs[TB * T_STEPS];   // staged x tile: xs[b][t]  (16 KB)
    __shared__ float h0s[TB * P0];       // layer0 h_{t-1} (pads zero)
    __shared__ float hc1[TB * P1];       // [h0_t(50) | h1_{t-1}(50) | pad4]
    __shared__ float gp[2 * TB * GP];    // partial gates: [khalf][row][200]

    const int tid  = threadIdx.x;
    const int lane = tid & 63;
    const int w    = tid >> 6;          // wave 0..7
    const int q    = w & 3;             // gate quarter
    const int m    = w >> 2;            // k-half 0/1
    const int b0   = blockIdx.x * TB;

    // ---- stage x tile (rows b0..b0+7 contiguous in x since IN==1) ----
    {
        const float4* xsrc4 = (const float4*)(x + b0 * T_STEPS);
        float4* xdst4 = (float4*)xs;
        #pragma unroll
        for (int k = 0; k < (TB * T_STEPS / 4) / 512; ++k)
            xdst4[tid + k * 512] = xsrc4[tid + k * 512];
    }

    // ---- zero-init LDS h-state (incl. pads; pads never written again) ----
    for (int i = tid; i < TB * P0; i += 512) h0s[i] = 0.0f;
    for (int i = tid; i < TB * P1; i += 512) hc1[i] = 0.0f;

    // ---- weight half-rows into explicit float4 registers (once) ----
    const bool is_gate = (lane < HID);
    const int  g = 50 * q + (is_gate ? lane : 49);   // clamped, uniform control

    auto ld0 = [&](int k) -> float {        // W_hh0 half (28 floats, pads 0)
        const int kk = m * 28 + k;
        return (kk < HID) ? W_hh0[g * HID + kk] : 0.0f;
    };
    auto ld1 = [&](int k) -> float {        // [W_ih1|W_hh1] half (52 floats)
        const int kk = m * 52 + k;
        if (kk < HID)     return W_ih1[g * HID + kk];
        if (kk < 2 * HID) return W_hh1[g * HID + kk - HID];
        return 0.0f;
    };

    #define DECL0(i) float4 W0_##i;
    #define DECL1(i) float4 W1_##i;
    L7(DECL0)
    L13(DECL1)
    #define LOAD0(i) W0_##i = make_float4(ld0(4*(i)), ld0(4*(i)+1), ld0(4*(i)+2), ld0(4*(i)+3));
    #define LOAD1(i) W1_##i = make_float4(ld1(4*(i)), ld1(4*(i)+1), ld1(4*(i)+2), ld1(4*(i)+3));
    L7(LOAD0)
    L13(LOAD1)

    float wih0 = W_ih0[g];
    float bs0  = b_ih0[g] + b_hh0[g];
    float bs1  = b_ih1[g] + b_hh1[g];

    // ---- PIN: opaque pass-through; compiler can no longer re-load these ----
    #define PIN4(v) asm volatile("" : "+v"(v.x), "+v"(v.y), "+v"(v.z), "+v"(v.w));
    #define PIN0(i) PIN4(W0_##i)
    #define PIN1(i) PIN4(W1_##i)
    L7(PIN0)
    L13(PIN1)
    asm volatile("" : "+v"(wih0), "+v"(bs0), "+v"(bs1));

    // elementwise state: thread (w, lane<50) owns c[row=w][k=lane], one per layer
    float c0 = 0.0f, c1 = 0.0f;

    __syncthreads();

    #define FMA0(i) { float4 hv = h4[i]; \
                      ax = fmaf(W0_##i.x, hv.x, ax); ay = fmaf(W0_##i.y, hv.y, ay); \
                      az = fmaf(W0_##i.z, hv.z, az); aw = fmaf(W0_##i.w, hv.w, aw); }
    #define FMA1(i) { float4 hv = h4[i]; \
                      ax = fmaf(W1_##i.x, hv.x, ax); ay = fmaf(W1_##i.y, hv.y, ay); \
                      az = fmaf(W1_##i.z, hv.z, az); aw = fmaf(W1_##i.w, hv.w, aw); }

    for (int t = 0; t < T_STEPS; ++t) {
        // ---------- Phase A: layer-0 partial gates ----------
        #pragma unroll
        for (int bb = 0; bb < TB; ++bb) {
            const float4* h4 = (const float4*)(h0s + bb * P0) + m * 7;
            float ax = 0.f, ay = 0.f, az = 0.f, aw = 0.f;
            L7(FMA0)
            float acc = (ax + ay) + (az + aw);
            if (m == 0) acc = fmaf(wih0, xs[bb * T_STEPS + t], acc + bs0);
            if (is_gate) gp[(m * TB + bb) * GP + g] = acc;
        }
        __syncthreads();

        // ---------- Phase B: layer-0 elementwise (row = wave id) ----------
        if (is_gate) {
            const int r = w;
            const float* g0 = gp + r * GP;
            const float* g1 = gp + (TB + r) * GP;
            const float gi = g0[lane]       + g1[lane];
            const float gf = g0[lane + 50]  + g1[lane + 50];
            const float gc = g0[lane + 100] + g1[lane + 100];
            const float go = g0[lane + 150] + g1[lane + 150];
            const float i_ = sigm(gi);
            const float f_ = sigm(gf);
            const float c_ = tanhh(gc);
            const float o_ = sigm(go);
            c0 = f_ * c0 + i_ * c_;
            const float hn = o_ * tanhh(c0);
            h0s[r * P0 + lane] = hn;   // next step's layer-0 recurrence
            hc1[r * P1 + lane] = hn;   // layer-1 input (this step)
        }
        __syncthreads();

        // ---------- Phase C: layer-1 partial gates ----------
        #pragma unroll
        for (int bb = 0; bb < TB; ++bb) {
            const float4* h4 = (const float4*)(hc1 + bb * P1 + m * 52);
            float ax = 0.f, ay = 0.f, az = 0.f, aw = 0.f;
            L13(FMA1)
            float acc = (ax + ay) + (az + aw);
            if (m == 0) acc += bs1;
            if (is_gate) gp[(m * TB + bb) * GP + g] = acc;
        }
        __syncthreads();

        // ---------- Phase D: layer-1 elementwise ----------
        if (is_gate) {
            const int r = w;
            const float* g0 = gp + r * GP;
            const float* g1 = gp + (TB + r) * GP;
            const float gi = g0[lane]       + g1[lane];
            const float gf = g0[lane + 50]  + g1[lane + 50];
            const float gc = g0[lane + 100] + g1[lane + 100];
            const float go = g0[lane + 150] + g1[lane + 150];
            const float i_ = sigm(gi);
            const float f_ = sigm(gf);
            const float c_ = tanhh(gc);
            const float o_ = sigm(go);
            c1 = f_ * c1 + i_ * c_;
            const float hn = o_ * tanhh(c1);
            hc1[r * P1 + 50 + lane] = hn;   // h1_t -> next step
        }
        __syncthreads();
    }

    // ---------- Final FC: out[b] = fc_b + fc_w . h1_{T-1}[b,:] ----------
    if (tid < TB) {
        const int b = tid;
        float s = fc_b[0];
        for (int k = 0; k < HID; ++k)
            s += fc_w[k] * hc1[b * P1 + 50 + k];
        out[b0 + b] = s;
    }
}

extern "C" void kernel_launch(void* const* d_in, const int* in_sizes, int n_in,
                              void* d_out, int out_size, void* d_ws, size_t ws_size,
                              hipStream_t stream) {
    (void)in_sizes; (void)n_in; (void)d_ws; (void)ws_size; (void)out_size;
    const float* x     = (const float*)d_in[0];
    const float* W_ih0 = (const float*)d_in[1];
    const float* W_hh0 = (const float*)d_in[2];
    const float* b_ih0 = (const float*)d_in[3];
    const float* b_hh0 = (const float*)d_in[4];
    const float* W_ih1 = (const float*)d_in[5];
    const float* W_hh1 = (const float*)d_in[6];
    const float* b_ih1 = (const float*)d_in[7];
    const float* b_hh1 = (const float*)d_in[8];
    const float* fc_w  = (const float*)d_in[9];
    const float* fc_b  = (const float*)d_in[10];

    dim3 grid(4096 / TB);   // 512 blocks, 2 per CU
    dim3 block(512);        // 8 waves
    lstm2_fc_kernel<<<grid, block, 0, stream>>>(
        x, W_ih0, W_hh0, b_ih0, b_hh0,
        W_ih1, W_hh1, b_ih1, b_hh1,
        fc_w, fc_b, (float*)d_out);
}

// Round 7
// 1041.123 us; speedup vs baseline: 5.5756x; 5.5756x over previous
//
#include <hip/hip_runtime.h>

// LSTMPricePredictor: B=4096, T=512, IN=1, H=50, 2 layers + FC(50->1)
// R7: MFMA pivot. R1-R6 proved the fp32-vector design can't hold 80 weight
//   floats/thread resident (compiler re-streams from L1 -> 4.5 ms wall, or
//   spills under a cap -> 6 ms). MFMA needs only 12 B-fragments = 48 VGPRs
//   of weights per wave -- pinned via asm, NO VGPR cap -> resident.
// Structure: 256 blocks (1/CU) x 512 threads (8 waves). Each block owns 16
//   batch rows. Per step, per layer: gates(16x200) = A(16xK) @ B(KxN) via
//   mfma_f32_16x16x32_f16; wave w owns N-tiles {2w, 2w+1} (N padded to 256,
//   zero weights beyond 200; C stored only for n<208).
//   - A = h state, fp16, in LDS in A-fragment order (lane packet = 16 B).
//   - Layer-0 K: 64 (h0 in k<50, x folded at k=50 with B-row = W_ih0).
//   - Layer-1: two chained GEMMs, A=h0_t (K64) and A=h1_{t-1} (K64).
//   - Biases folded into MFMA acc-init (per-lane, depends only on n).
//   - C routed through LDS (pitch 19, conflict-benign) to the elementwise
//     phase: thread tid owns cells (m=tid&15, k=tid>>4) and (m, k+32).
//   - c-state fp32 in registers; h written back as fp16 into A-frag LDS.
// Precision: fp16 weights/h (11-bit mantissa), fp32 accum everywhere ->
//   est. output err ~1e-4 vs 1.63e-3 threshold. (bf16 would be ~16x worse.)

typedef _Float16 half8 __attribute__((ext_vector_type(8)));
typedef float    f32x4 __attribute__((ext_vector_type(4)));

#define TT   512
#define HID  50
#define NG   200        // 4*H
#define NROW 16         // batch rows per block (= M tile)
#define CP   19         // C_lds pitch in floats (bank-spreading)

__device__ __forceinline__ float sigm(float v)  { return 1.0f / (1.0f + __expf(-v)); }
__device__ __forceinline__ float tanhh(float v) { return 1.0f - 2.0f / (1.0f + __expf(2.0f * v)); }

// Build one B-fragment (lane's 8 fp16) for tile column n, K-chunk `chunk`.
// B[kk][n] = W[n*50+kk] for kk<50; layer-0 additionally folds W_ih0 at kk==50
// (the x slot). Everything else (n>=200, kk pad) is zero.
__device__ __forceinline__ float4 make_frag(const float* W, const float* Wx,
                                            int n, int chunk, int lane, bool foldx) {
    half8 hv = {};
    #pragma unroll
    for (int j = 0; j < 8; ++j) {
        const int kk = 32 * chunk + 8 * (lane >> 4) + j;
        float v = 0.0f;
        if (n < NG) {
            if (kk < HID)                v = W[n * HID + kk];
            else if (foldx && kk == HID) v = Wx[n];
        }
        hv[j] = (_Float16)v;
    }
    return __builtin_bit_cast(float4, hv);
}

#define PIN(f) asm volatile("" : "+v"(f.x), "+v"(f.y), "+v"(f.z), "+v"(f.w));
#define MFMA(a, bf, c) __builtin_amdgcn_mfma_f32_16x16x32_f16((a), __builtin_bit_cast(half8, (bf)), (c), 0, 0, 0)

extern "C" __global__ __launch_bounds__(512)
void lstm2_mfma_kernel(const float* __restrict__ x,
                       const float* __restrict__ W_ih0, const float* __restrict__ W_hh0,
                       const float* __restrict__ b_ih0, const float* __restrict__ b_hh0,
                       const float* __restrict__ W_ih1, const float* __restrict__ W_hh1,
                       const float* __restrict__ b_ih1, const float* __restrict__ b_hh1,
                       const float* __restrict__ fc_w, const float* __restrict__ fc_b,
                       float* __restrict__ out)
{
    // A-frag buffers: 2 K-chunks x 64 lanes x 8 fp16 = 1024 f16 each.
    __shared__ _Float16 Ah0[1024];     // h0 (k<50) + x slot (k=50, written as x_{t})
    __shared__ _Float16 Ah1[1024];     // h1 (k<50)
    __shared__ float    Cls[208 * CP]; // gate pre-activations, [n][m] pitch CP
    __shared__ float    hfin[HID * NROW]; // final-step h1 (fp32) for the FC

    const int tid  = threadIdx.x;
    const int lane = tid & 63;
    const int w    = tid >> 6;                 // wave 0..7
    const int b0   = blockIdx.x * NROW;

    // zero A buffers (pads beyond k<50 / x-slot stay zero forever)
    for (int i = tid; i < 1024; i += 512) { Ah0[i] = (_Float16)0.f; Ah1[i] = (_Float16)0.f; }

    // ---- per-wave B fragments: tiles 2w (A) and 2w+1 (B) ----
    const int n0a = 32 * w, n0b = 32 * w + 16;
    const int nA = n0a + (lane & 15), nB = n0b + (lane & 15);

    float4 B0A0 = make_frag(W_hh0, W_ih0, nA, 0, lane, true);
    float4 B0A1 = make_frag(W_hh0, W_ih0, nA, 1, lane, true);
    float4 B0B0 = make_frag(W_hh0, W_ih0, nB, 0, lane, true);
    float4 B0B1 = make_frag(W_hh0, W_ih0, nB, 1, lane, true);
    float4 BiA0 = make_frag(W_ih1, W_ih1, nA, 0, lane, false);
    float4 BiA1 = make_frag(W_ih1, W_ih1, nA, 1, lane, false);
    float4 BiB0 = make_frag(W_ih1, W_ih1, nB, 0, lane, false);
    float4 BiB1 = make_frag(W_ih1, W_ih1, nB, 1, lane, false);
    float4 BhA0 = make_frag(W_hh1, W_hh1, nA, 0, lane, false);
    float4 BhA1 = make_frag(W_hh1, W_hh1, nA, 1, lane, false);
    float4 BhB0 = make_frag(W_hh1, W_hh1, nB, 0, lane, false);
    float4 BhB1 = make_frag(W_hh1, W_hh1, nB, 1, lane, false);
    PIN(B0A0) PIN(B0A1) PIN(B0B0) PIN(B0B1)
    PIN(BiA0) PIN(BiA1) PIN(BiB0) PIN(BiB1)
    PIN(BhA0) PIN(BhA1) PIN(BhB0) PIN(BhB1)

    // biases folded into acc-init (depend only on n)
    const float biasA0 = (nA < NG) ? b_ih0[nA] + b_hh0[nA] : 0.f;
    const float biasB0 = (nB < NG) ? b_ih0[nB] + b_hh0[nB] : 0.f;
    const float biasA1 = (nA < NG) ? b_ih1[nA] + b_hh1[nA] : 0.f;
    const float biasB1 = (nB < NG) ? b_ih1[nB] + b_hh1[nB] : 0.f;

    // x_0 into the x slot (cell (m, k=50): chunk1, lane'=32+m, j=2)
    if (tid < NROW) Ah0[512 + (32 + tid) * 8 + 2] = (_Float16)x[(size_t)(b0 + tid) * TT];

    // elementwise cell ownership
    const int m  = tid & 15;
    const int k1 = tid >> 4;            // 0..31
    const int k2 = k1 + 32;             // 32..63
    const bool has2 = (k2 < HID);
    float c01 = 0.f, c02 = 0.f, c11 = 0.f, c12 = 0.f;

    const int  mr     = 4 * (lane >> 4);
    const bool storeA = (n0a < 208);    // waves 0..6 tileA; wave7 skips
    const bool storeB = (n0b < 208);    // waves 0..5 tileB

    __syncthreads();

    for (int t = 0; t < TT; ++t) {
        // ---------- P1: layer-0 GEMM (h0_{t-1}, x_t already in Ah0) ----------
        {
            half8 a0 = *(half8*)(Ah0 + lane * 8);
            half8 a1 = *(half8*)(Ah0 + 512 + lane * 8);
            f32x4 accA = {biasA0, biasA0, biasA0, biasA0};
            f32x4 accB = {biasB0, biasB0, biasB0, biasB0};
            accA = MFMA(a0, B0A0, accA);
            accB = MFMA(a0, B0B0, accB);
            accA = MFMA(a1, B0A1, accA);
            accB = MFMA(a1, B0B1, accB);
            if (storeA) {
                #pragma unroll
                for (int r = 0; r < 4; ++r) Cls[nA * CP + mr + r] = accA[r];
            }
            if (storeB) {
                #pragma unroll
                for (int r = 0; r < 4; ++r) Cls[nB * CP + mr + r] = accB[r];
            }
        }
        __syncthreads();

        // ---------- P2: layer-0 elementwise ----------
        {
            {
                const float zi = Cls[(0 * HID + k1) * CP + m];
                const float zf = Cls[(1 * HID + k1) * CP + m];
                const float zg = Cls[(2 * HID + k1) * CP + m];
                const float zo = Cls[(3 * HID + k1) * CP + m];
                c01 = sigm(zf) * c01 + sigm(zi) * tanhh(zg);
                const float h = sigm(zo) * tanhh(c01);
                Ah0[((((k1 & 31) >> 3) << 4) + m) * 8 + (k1 & 7)] = (_Float16)h; // k1<32 -> chunk0
            }
            if (has2) {
                const float zi = Cls[(0 * HID + k2) * CP + m];
                const float zf = Cls[(1 * HID + k2) * CP + m];
                const float zg = Cls[(2 * HID + k2) * CP + m];
                const float zo = Cls[(3 * HID + k2) * CP + m];
                c02 = sigm(zf) * c02 + sigm(zi) * tanhh(zg);
                const float h = sigm(zo) * tanhh(c02);
                Ah0[512 + ((((k2 & 31) >> 3) << 4) + m) * 8 + (k2 & 7)] = (_Float16)h; // chunk1
            }
        }
        __syncthreads();

        // ---------- P3: layer-1 GEMM: W_ih1 @ h0_t + W_hh1 @ h1_{t-1} ----------
        {
            half8 a00 = *(half8*)(Ah0 + lane * 8);
            half8 a01 = *(half8*)(Ah0 + 512 + lane * 8);   // x slot hits zero B rows
            half8 a10 = *(half8*)(Ah1 + lane * 8);
            half8 a11 = *(half8*)(Ah1 + 512 + lane * 8);
            f32x4 accA = {biasA1, biasA1, biasA1, biasA1};
            f32x4 accB = {biasB1, biasB1, biasB1, biasB1};
            accA = MFMA(a00, BiA0, accA);
            accB = MFMA(a00, BiB0, accB);
            accA = MFMA(a01, BiA1, accA);
            accB = MFMA(a01, BiB1, accB);
            accA = MFMA(a10, BhA0, accA);
            accB = MFMA(a10, BhB0, accB);
            accA = MFMA(a11, BhA1, accA);
            accB = MFMA(a11, BhB1, accB);
            if (storeA) {
                #pragma unroll
                for (int r = 0; r < 4; ++r) Cls[nA * CP + mr + r] = accA[r];
            }
            if (storeB) {
                #pragma unroll
                for (int r = 0; r < 4; ++r) Cls[nB * CP + mr + r] = accB[r];
            }
        }
        __syncthreads();

        // ---------- P4: layer-1 elementwise (+ x prefetch for t+1) ----------
        {
            {
                const float zi = Cls[(0 * HID + k1) * CP + m];
                const float zf = Cls[(1 * HID + k1) * CP + m];
                const float zg = Cls[(2 * HID + k1) * CP + m];
                const float zo = Cls[(3 * HID + k1) * CP + m];
                c11 = sigm(zf) * c11 + sigm(zi) * tanhh(zg);
                const float h = sigm(zo) * tanhh(c11);
                Ah1[((((k1 & 31) >> 3) << 4) + m) * 8 + (k1 & 7)] = (_Float16)h;
                hfin[k1 * NROW + m] = h;
            }
            if (has2) {
                const float zi = Cls[(0 * HID + k2) * CP + m];
                const float zf = Cls[(1 * HID + k2) * CP + m];
                const float zg = Cls[(2 * HID + k2) * CP + m];
                const float zo = Cls[(3 * HID + k2) * CP + m];
                c12 = sigm(zf) * c12 + sigm(zi) * tanhh(zg);
                const float h = sigm(zo) * tanhh(c12);
                Ah1[512 + ((((k2 & 31) >> 3) << 4) + m) * 8 + (k2 & 7)] = (_Float16)h;
                hfin[k2 * NROW + m] = h;
            }
            if (tid < NROW && (t + 1) < TT)
                Ah0[512 + (32 + tid) * 8 + 2] = (_Float16)x[(size_t)(b0 + tid) * TT + t + 1];
        }
        __syncthreads();
    }

    // ---------- FC epilogue: out[b] = fc_b + fc_w . h1_{T-1}[b,:] ----------
    if (tid < NROW) {
        float s = fc_b[0];
        for (int k = 0; k < HID; ++k)
            s += fc_w[k] * hfin[k * NROW + tid];
        out[b0 + tid] = s;
    }
}

extern "C" void kernel_launch(void* const* d_in, const int* in_sizes, int n_in,
                              void* d_out, int out_size, void* d_ws, size_t ws_size,
                              hipStream_t stream) {
    (void)in_sizes; (void)n_in; (void)d_ws; (void)ws_size; (void)out_size;
    const float* x     = (const float*)d_in[0];
    const float* W_ih0 = (const float*)d_in[1];
    const float* W_hh0 = (const float*)d_in[2];
    const float* b_ih0 = (const float*)d_in[3];
    const float* b_hh0 = (const float*)d_in[4];
    const float* W_ih1 = (const float*)d_in[5];
    const float* W_hh1 = (const float*)d_in[6];
    const float* b_ih1 = (const float*)d_in[7];
    const float* b_hh1 = (const float*)d_in[8];
    const float* fc_w  = (const float*)d_in[9];
    const float* fc_b  = (const float*)d_in[10];

    dim3 grid(4096 / NROW);   // 256 blocks, 1 per CU
    dim3 block(512);          // 8 waves
    lstm2_mfma_kernel<<<grid, block, 0, stream>>>(
        x, W_ih0, W_hh0, b_ih0, b_hh0,
        W_ih1, W_hh1, b_ih1, b_hh1,
        fc_w, fc_b, (float*)d_out);
}

// Round 8
// 994.826 us; speedup vs baseline: 5.8350x; 1.0465x over previous
//
#include <hip/hip_runtime.h>

// LSTMPricePredictor: B=4096, T=512, IN=1, H=50, 2 layers + FC(50->1)
// R8: cross-layer software pipeline on the R7 MFMA structure.
//   R7 (1041 us, passed, absmax 4.9e-4): 4 barrier-phases/step, per-step
//   critical path 4941 cyc, VALUBusy 51%, MfmaUtil 8%. The two GEMMs
//   (layer-0 at step u, layer-1 at step u-1) share input h0^(u) and are
//   independent -> merge into ONE GEMM phase; both elementwise updates are
//   independent -> ONE EW phase. 513 iters x 2 barriers (was 512 x 4).
// Iteration u (0..512):
//   GEMM: gates0^(u) = W0.[h0^(u); x_u]          (skip at u=TT)
//         gates1^(u-1) = Wi1.h0^(u) + Wh1.h1^(u-1) (skip at u=0)
//   EW:   c0/h0 -> h0^(u+1) in Ah0; c1/h1 -> h1^(u) in Ah1; prefetch x_{u+1}.
// All layout/fragment machinery identical to R7 (verified by its pass).

typedef _Float16 half8 __attribute__((ext_vector_type(8)));
typedef float    f32x4 __attribute__((ext_vector_type(4)));

#define TT   512
#define HID  50
#define NG   200        // 4*H
#define NROW 16         // batch rows per block (= M tile)
#define CP   19         // C_lds pitch in floats (bank-spreading)

__device__ __forceinline__ float sigm(float v)  { return 1.0f / (1.0f + __expf(-v)); }
__device__ __forceinline__ float tanhh(float v) { return 1.0f - 2.0f / (1.0f + __expf(2.0f * v)); }

// B-fragment (lane's 8 fp16) for tile column n, K-chunk `chunk`.
// B[kk][n] = W[n*50+kk] for kk<50; layer-0 folds W_ih0 at kk==50 (x slot).
__device__ __forceinline__ float4 make_frag(const float* W, const float* Wx,
                                            int n, int chunk, int lane, bool foldx) {
    half8 hv = {};
    #pragma unroll
    for (int j = 0; j < 8; ++j) {
        const int kk = 32 * chunk + 8 * (lane >> 4) + j;
        float v = 0.0f;
        if (n < NG) {
            if (kk < HID)                v = W[n * HID + kk];
            else if (foldx && kk == HID) v = Wx[n];
        }
        hv[j] = (_Float16)v;
    }
    return __builtin_bit_cast(float4, hv);
}

#define PIN(f) asm volatile("" : "+v"(f.x), "+v"(f.y), "+v"(f.z), "+v"(f.w));
#define MFMA(a, bf, c) __builtin_amdgcn_mfma_f32_16x16x32_f16((a), __builtin_bit_cast(half8, (bf)), (c), 0, 0, 0)

extern "C" __global__ __launch_bounds__(512, 2)
void lstm2_mfma_kernel(const float* __restrict__ x,
                       const float* __restrict__ W_ih0, const float* __restrict__ W_hh0,
                       const float* __restrict__ b_ih0, const float* __restrict__ b_hh0,
                       const float* __restrict__ W_ih1, const float* __restrict__ W_hh1,
                       const float* __restrict__ b_ih1, const float* __restrict__ b_hh1,
                       const float* __restrict__ fc_w, const float* __restrict__ fc_b,
                       float* __restrict__ out)
{
    __shared__ _Float16 Ah0[1024];        // h0 (k<50) + x slot (k=50)
    __shared__ _Float16 Ah1[1024];        // h1 (k<50)
    __shared__ float    Cls[416 * CP];    // rows 0..207: layer-0, 208..415: layer-1
    __shared__ float    hfin[HID * NROW]; // final h1 (fp32) for the FC

    const int tid  = threadIdx.x;
    const int lane = tid & 63;
    const int w    = tid >> 6;                 // wave 0..7
    const int b0   = blockIdx.x * NROW;

    for (int i = tid; i < 1024; i += 512) { Ah0[i] = (_Float16)0.f; Ah1[i] = (_Float16)0.f; }

    // ---- per-wave B fragments: tiles 2w (A) and 2w+1 (B) ----
    const int n0a = 32 * w, n0b = 32 * w + 16;
    const int nA = n0a + (lane & 15), nB = n0b + (lane & 15);

    float4 B0A0 = make_frag(W_hh0, W_ih0, nA, 0, lane, true);
    float4 B0A1 = make_frag(W_hh0, W_ih0, nA, 1, lane, true);
    float4 B0B0 = make_frag(W_hh0, W_ih0, nB, 0, lane, true);
    float4 B0B1 = make_frag(W_hh0, W_ih0, nB, 1, lane, true);
    float4 BiA0 = make_frag(W_ih1, W_ih1, nA, 0, lane, false);
    float4 BiA1 = make_frag(W_ih1, W_ih1, nA, 1, lane, false);
    float4 BiB0 = make_frag(W_ih1, W_ih1, nB, 0, lane, false);
    float4 BiB1 = make_frag(W_ih1, W_ih1, nB, 1, lane, false);
    float4 BhA0 = make_frag(W_hh1, W_hh1, nA, 0, lane, false);
    float4 BhA1 = make_frag(W_hh1, W_hh1, nA, 1, lane, false);
    float4 BhB0 = make_frag(W_hh1, W_hh1, nB, 0, lane, false);
    float4 BhB1 = make_frag(W_hh1, W_hh1, nB, 1, lane, false);
    PIN(B0A0) PIN(B0A1) PIN(B0B0) PIN(B0B1)
    PIN(BiA0) PIN(BiA1) PIN(BiB0) PIN(BiB1)
    PIN(BhA0) PIN(BhA1) PIN(BhB0) PIN(BhB1)

    const float biasA0 = (nA < NG) ? b_ih0[nA] + b_hh0[nA] : 0.f;
    const float biasB0 = (nB < NG) ? b_ih0[nB] + b_hh0[nB] : 0.f;
    const float biasA1 = (nA < NG) ? b_ih1[nA] + b_hh1[nA] : 0.f;
    const float biasB1 = (nB < NG) ? b_ih1[nB] + b_hh1[nB] : 0.f;

    // x_0 into the x slot (cell (m, k=50): chunk1, lane'=32+m, j=2)
    if (tid < NROW) Ah0[512 + (32 + tid) * 8 + 2] = (_Float16)x[(size_t)(b0 + tid) * TT];

    // elementwise cell ownership
    const int m  = tid & 15;
    const int k1 = tid >> 4;            // 0..31
    const int k2 = k1 + 32;             // 32..63
    const bool has2 = (k2 < HID);
    float c01 = 0.f, c02 = 0.f, c11 = 0.f, c12 = 0.f;

    const int  mr     = 4 * (lane >> 4);
    const bool storeA = (n0a < 208);
    const bool storeB = (n0b < 208);

    float* C0 = Cls;             // layer-0 gate rows
    float* C1 = Cls + 208 * CP;  // layer-1 gate rows

    __syncthreads();

    for (int u = 0; u <= TT; ++u) {
        // ================= GEMM phase =================
        half8 a00 = *(half8*)(Ah0 + lane * 8);
        half8 a01 = *(half8*)(Ah0 + 512 + lane * 8);

        if (u != TT) {   // layer-0: gates0^(u) from [h0^(u); x_u]
            f32x4 accA = {biasA0, biasA0, biasA0, biasA0};
            f32x4 accB = {biasB0, biasB0, biasB0, biasB0};
            accA = MFMA(a00, B0A0, accA);
            accB = MFMA(a00, B0B0, accB);
            accA = MFMA(a01, B0A1, accA);
            accB = MFMA(a01, B0B1, accB);
            if (storeA) {
                #pragma unroll
                for (int r = 0; r < 4; ++r) C0[nA * CP + mr + r] = accA[r];
            }
            if (storeB) {
                #pragma unroll
                for (int r = 0; r < 4; ++r) C0[nB * CP + mr + r] = accB[r];
            }
        }
        if (u != 0) {    // layer-1: gates1^(u-1) = Wi1.h0^(u) + Wh1.h1^(u-1)
            half8 a10 = *(half8*)(Ah1 + lane * 8);
            half8 a11 = *(half8*)(Ah1 + 512 + lane * 8);
            f32x4 accA = {biasA1, biasA1, biasA1, biasA1};
            f32x4 accB = {biasB1, biasB1, biasB1, biasB1};
            accA = MFMA(a00, BiA0, accA);
            accB = MFMA(a00, BiB0, accB);
            accA = MFMA(a01, BiA1, accA);
            accB = MFMA(a01, BiB1, accB);
            accA = MFMA(a10, BhA0, accA);
            accB = MFMA(a10, BhB0, accB);
            accA = MFMA(a11, BhA1, accA);
            accB = MFMA(a11, BhB1, accB);
            if (storeA) {
                #pragma unroll
                for (int r = 0; r < 4; ++r) C1[nA * CP + mr + r] = accA[r];
            }
            if (storeB) {
                #pragma unroll
                for (int r = 0; r < 4; ++r) C1[nB * CP + mr + r] = accB[r];
            }
        }
        __syncthreads();

        // ================= EW phase =================
        if (u != TT) {   // layer-0 update -> h0^(u+1)
            {
                const float zi = C0[(0 * HID + k1) * CP + m];
                const float zf = C0[(1 * HID + k1) * CP + m];
                const float zg = C0[(2 * HID + k1) * CP + m];
                const float zo = C0[(3 * HID + k1) * CP + m];
                c01 = sigm(zf) * c01 + sigm(zi) * tanhh(zg);
                const float h = sigm(zo) * tanhh(c01);
                Ah0[((((k1 & 31) >> 3) << 4) + m) * 8 + (k1 & 7)] = (_Float16)h;
            }
            if (has2) {
                const float zi = C0[(0 * HID + k2) * CP + m];
                const float zf = C0[(1 * HID + k2) * CP + m];
                const float zg = C0[(2 * HID + k2) * CP + m];
                const float zo = C0[(3 * HID + k2) * CP + m];
                c02 = sigm(zf) * c02 + sigm(zi) * tanhh(zg);
                const float h = sigm(zo) * tanhh(c02);
                Ah0[512 + ((((k2 & 31) >> 3) << 4) + m) * 8 + (k2 & 7)] = (_Float16)h;
            }
            // prefetch x_{u+1} for the next GEMM's layer-0
            if (tid < NROW && (u + 1) < TT)
                Ah0[512 + (32 + tid) * 8 + 2] = (_Float16)x[(size_t)(b0 + tid) * TT + u + 1];
        }
        if (u != 0) {    // layer-1 update -> h1^(u)
            {
                const float zi = C1[(0 * HID + k1) * CP + m];
                const float zf = C1[(1 * HID + k1) * CP + m];
                const float zg = C1[(2 * HID + k1) * CP + m];
                const float zo = C1[(3 * HID + k1) * CP + m];
                c11 = sigm(zf) * c11 + sigm(zi) * tanhh(zg);
                const float h = sigm(zo) * tanhh(c11);
                Ah1[((((k1 & 31) >> 3) << 4) + m) * 8 + (k1 & 7)] = (_Float16)h;
                hfin[k1 * NROW + m] = h;
            }
            if (has2) {
                const float zi = C1[(0 * HID + k2) * CP + m];
                const float zf = C1[(1 * HID + k2) * CP + m];
                const float zg = C1[(2 * HID + k2) * CP + m];
                const float zo = C1[(3 * HID + k2) * CP + m];
                c12 = sigm(zf) * c12 + sigm(zi) * tanhh(zg);
                const float h = sigm(zo) * tanhh(c12);
                Ah1[512 + ((((k2 & 31) >> 3) << 4) + m) * 8 + (k2 & 7)] = (_Float16)h;
                hfin[k2 * NROW + m] = h;
            }
        }
        __syncthreads();
    }

    // ---------- FC epilogue: out[b] = fc_b + fc_w . h1^(TT)[b,:] ----------
    if (tid < NROW) {
        float s = fc_b[0];
        for (int k = 0; k < HID; ++k)
            s += fc_w[k] * hfin[k * NROW + tid];
        out[b0 + tid] = s;
    }
}

extern "C" void kernel_launch(void* const* d_in, const int* in_sizes, int n_in,
                              void* d_out, int out_size, void* d_ws, size_t ws_size,
                              hipStream_t stream) {
    (void)in_sizes; (void)n_in; (void)d_ws; (void)ws_size; (void)out_size;
    const float* x     = (const float*)d_in[0];
    const float* W_ih0 = (const float*)d_in[1];
    const float* W_hh0 = (const float*)d_in[2];
    const float* b_ih0 = (const float*)d_in[3];
    const float* b_hh0 = (const float*)d_in[4];
    const float* W_ih1 = (const float*)d_in[5];
    const float* W_hh1 = (const float*)d_in[6];
    const float* b_ih1 = (const float*)d_in[7];
    const float* b_hh1 = (const float*)d_in[8];
    const float* fc_w  = (const float*)d_in[9];
    const float* fc_b  = (const float*)d_in[10];

    dim3 grid(4096 / NROW);   // 256 blocks, 1 per CU
    dim3 block(512);          // 8 waves
    lstm2_mfma_kernel<<<grid, block, 0, stream>>>(
        x, W_ih0, W_hh0, b_ih0, b_hh0,
        W_ih1, W_hh1, b_ih1, b_hh1,
        fc_w, fc_b, (float*)d_out);
}

// Round 9
// 867.533 us; speedup vs baseline: 6.6912x; 1.1467x over previous
//
#include <hip/hip_runtime.h>

// LSTMPricePredictor: B=4096, T=512, IN=1, H=50, 2 layers + FC(50->1)
// R9: occupancy attack. R8 (995 us) showed barriers weren't the wall --
//   latency chains at 2 waves/SIMD were (VALUBusy 53%, per-step 4660 cyc
//   vs ~600 cyc compute floor). Same merged 2-barrier pipeline, but:
//   - 1024 threads = 16 waves = 4 waves/SIMD (2x latency overlap).
//   - GEMM: wave wv owns ONE 16-wide N-tile (13 active tiles cover N=208);
//     6 B-frags = 24 VGPRs/wave, pinned.
//   - EW rebalanced: layer-0 cells on threads 0..799, layer-1 cells on
//     threads 224..1023 -> every wave does <=2 cell updates (was 4).
// Iteration u (0..512):
//   GEMM: gates0^(u) = W0.[h0^(u); x_u]            (skip at u=TT)
//         gates1^(u-1) = Wi1.h0^(u) + Wh1.h1^(u-1)  (skip at u=0)
//   EW:   h0^(u+1) -> Ah0, h1^(u) -> Ah1, prefetch x_{u+1}.
// Fragment/layout machinery identical to R7/R8 (both passed, absmax 4.9e-4).

typedef _Float16 half8 __attribute__((ext_vector_type(8)));
typedef float    f32x4 __attribute__((ext_vector_type(4)));

#define TT   512
#define HID  50
#define NG   200        // 4*H
#define NROW 16         // batch rows per block (= M tile)
#define CP   19         // C_lds pitch in floats (bank-spreading)

__device__ __forceinline__ float sigm(float v)  { return 1.0f / (1.0f + __expf(-v)); }
__device__ __forceinline__ float tanhh(float v) { return 1.0f - 2.0f / (1.0f + __expf(2.0f * v)); }

// B-fragment (lane's 8 fp16) for tile column n, K-chunk `chunk`.
// B[kk][n] = W[n*50+kk] for kk<50; layer-0 folds W_ih0 at kk==50 (x slot).
__device__ __forceinline__ float4 make_frag(const float* W, const float* Wx,
                                            int n, int chunk, int lane, bool foldx) {
    half8 hv = {};
    #pragma unroll
    for (int j = 0; j < 8; ++j) {
        const int kk = 32 * chunk + 8 * (lane >> 4) + j;
        float v = 0.0f;
        if (n < NG) {
            if (kk < HID)                v = W[n * HID + kk];
            else if (foldx && kk == HID) v = Wx[n];
        }
        hv[j] = (_Float16)v;
    }
    return __builtin_bit_cast(float4, hv);
}

#define PIN(f) asm volatile("" : "+v"(f.x), "+v"(f.y), "+v"(f.z), "+v"(f.w));
#define MFMA(a, bf, c) __builtin_amdgcn_mfma_f32_16x16x32_f16((a), __builtin_bit_cast(half8, (bf)), (c), 0, 0, 0)

extern "C" __global__ __launch_bounds__(1024)
void lstm2_mfma_kernel(const float* __restrict__ x,
                       const float* __restrict__ W_ih0, const float* __restrict__ W_hh0,
                       const float* __restrict__ b_ih0, const float* __restrict__ b_hh0,
                       const float* __restrict__ W_ih1, const float* __restrict__ W_hh1,
                       const float* __restrict__ b_ih1, const float* __restrict__ b_hh1,
                       const float* __restrict__ fc_w, const float* __restrict__ fc_b,
                       float* __restrict__ out)
{
    __shared__ _Float16 Ah0[1024];        // h0 (k<50) + x slot (k=50)
    __shared__ _Float16 Ah1[1024];        // h1 (k<50)
    __shared__ float    Cls[416 * CP];    // rows 0..207: layer-0, 208..415: layer-1
    __shared__ float    hfin[HID * NROW]; // final h1 (fp32) for the FC

    const int tid  = threadIdx.x;
    const int lane = tid & 63;
    const int wv   = tid >> 6;                 // wave 0..15
    const int b0   = blockIdx.x * NROW;

    if (tid < 1024) { Ah0[tid] = (_Float16)0.f; Ah1[tid] = (_Float16)0.f; }

    // ---- per-wave B fragments: ONE tile per wave ----
    const int n0 = 16 * wv;
    const int nA = n0 + (lane & 15);
    const bool tile_on = (n0 < 208);           // waves 13..15 idle in GEMM

    float4 B0A0 = make_frag(W_hh0, W_ih0, nA, 0, lane, true);
    float4 B0A1 = make_frag(W_hh0, W_ih0, nA, 1, lane, true);
    float4 BiA0 = make_frag(W_ih1, W_ih1, nA, 0, lane, false);
    float4 BiA1 = make_frag(W_ih1, W_ih1, nA, 1, lane, false);
    float4 BhA0 = make_frag(W_hh1, W_hh1, nA, 0, lane, false);
    float4 BhA1 = make_frag(W_hh1, W_hh1, nA, 1, lane, false);
    PIN(B0A0) PIN(B0A1) PIN(BiA0) PIN(BiA1) PIN(BhA0) PIN(BhA1)

    const float bias0 = (nA < NG) ? b_ih0[nA] + b_hh0[nA] : 0.f;
    const float bias1 = (nA < NG) ? b_ih1[nA] + b_hh1[nA] : 0.f;

    // x_0 into the x slot (cell (m, k=50): chunk1, lane'=32+m, j=2)
    if (tid < NROW) Ah0[512 + (32 + tid) * 8 + 2] = (_Float16)x[(size_t)(b0 + tid) * TT];

    // ---- EW cell ownership (balanced across all 16 waves) ----
    // layer-0: threads 0..799   -> cell (k0=t>>4, m0=t&15)
    // layer-1: threads 224..1023 -> j=t-224, cell (k1=j>>4, m1=j&15)
    const bool ew0 = (tid < 800);
    const int  k0 = tid >> 4, m0 = tid & 15;
    const int  j1 = tid - 224;
    const bool ew1 = (j1 >= 0);
    const int  k1 = j1 >> 4, m1 = j1 & 15;
    float c0 = 0.f, c1 = 0.f;

    const int mr = 4 * (lane >> 4);
    float* C0 = Cls;             // layer-0 gate rows
    float* C1 = Cls + 208 * CP;  // layer-1 gate rows

    __syncthreads();

    for (int u = 0; u <= TT; ++u) {
        // ================= GEMM phase =================
        if (tile_on) {
            half8 a00 = *(half8*)(Ah0 + lane * 8);
            half8 a01 = *(half8*)(Ah0 + 512 + lane * 8);
            if (u != TT) {   // layer-0: gates0^(u)
                f32x4 acc = {bias0, bias0, bias0, bias0};
                acc = MFMA(a00, B0A0, acc);
                acc = MFMA(a01, B0A1, acc);
                #pragma unroll
                for (int r = 0; r < 4; ++r) C0[nA * CP + mr + r] = acc[r];
            }
            if (u != 0) {    // layer-1: gates1^(u-1)
                half8 a10 = *(half8*)(Ah1 + lane * 8);
                half8 a11 = *(half8*)(Ah1 + 512 + lane * 8);
                f32x4 acc = {bias1, bias1, bias1, bias1};
                acc = MFMA(a00, BiA0, acc);
                acc = MFMA(a01, BiA1, acc);
                acc = MFMA(a10, BhA0, acc);
                acc = MFMA(a11, BhA1, acc);
                #pragma unroll
                for (int r = 0; r < 4; ++r) C1[nA * CP + mr + r] = acc[r];
            }
        }
        __syncthreads();

        // ================= EW phase =================
        float xr = 0.f;
        if (tid < NROW && (u + 1) < TT)
            xr = x[(size_t)(b0 + tid) * TT + u + 1];   // issue global load early

        if (u != TT && ew0) {   // layer-0 update -> h0^(u+1)
            const float zi = C0[(0 * HID + k0) * CP + m0];
            const float zf = C0[(1 * HID + k0) * CP + m0];
            const float zg = C0[(2 * HID + k0) * CP + m0];
            const float zo = C0[(3 * HID + k0) * CP + m0];
            c0 = sigm(zf) * c0 + sigm(zi) * tanhh(zg);
            const float h = sigm(zo) * tanhh(c0);
            const int klo = k0 & 31;
            Ah0[(k0 >> 5) * 512 + (((klo >> 3) << 4) + m0) * 8 + (klo & 7)] = (_Float16)h;
        }
        if (u != 0 && ew1) {    // layer-1 update -> h1^(u)
            const float zi = C1[(0 * HID + k1) * CP + m1];
            const float zf = C1[(1 * HID + k1) * CP + m1];
            const float zg = C1[(2 * HID + k1) * CP + m1];
            const float zo = C1[(3 * HID + k1) * CP + m1];
            c1 = sigm(zf) * c1 + sigm(zi) * tanhh(zg);
            const float h = sigm(zo) * tanhh(c1);
            const int klo = k1 & 31;
            Ah1[(k1 >> 5) * 512 + (((klo >> 3) << 4) + m1) * 8 + (klo & 7)] = (_Float16)h;
            hfin[k1 * NROW + m1] = h;
        }
        if (tid < NROW && (u + 1) < TT)
            Ah0[512 + (32 + tid) * 8 + 2] = (_Float16)xr;   // x_{u+1} slot
        __syncthreads();
    }

    // ---------- FC epilogue: out[b] = fc_b + fc_w . h1^(TT)[b,:] ----------
    if (tid < NROW) {
        float s = fc_b[0];
        for (int k = 0; k < HID; ++k)
            s += fc_w[k] * hfin[k * NROW + tid];
        out[b0 + tid] = s;
    }
}

extern "C" void kernel_launch(void* const* d_in, const int* in_sizes, int n_in,
                              void* d_out, int out_size, void* d_ws, size_t ws_size,
                              hipStream_t stream) {
    (void)in_sizes; (void)n_in; (void)d_ws; (void)ws_size; (void)out_size;
    const float* x     = (const float*)d_in[0];
    const float* W_ih0 = (const float*)d_in[1];
    const float* W_hh0 = (const float*)d_in[2];
    const float* b_ih0 = (const float*)d_in[3];
    const float* b_hh0 = (const float*)d_in[4];
    const float* W_ih1 = (const float*)d_in[5];
    const float* W_hh1 = (const float*)d_in[6];
    const float* b_ih1 = (const float*)d_in[7];
    const float* b_hh1 = (const float*)d_in[8];
    const float* fc_w  = (const float*)d_in[9];
    const float* fc_b  = (const float*)d_in[10];

    dim3 grid(4096 / NROW);   // 256 blocks, 1 per CU
    dim3 block(1024);         // 16 waves = 4 waves/SIMD
    lstm2_mfma_kernel<<<grid, block, 0, stream>>>(
        x, W_ih0, W_hh0, b_ih0, b_hh0,
        W_ih1, W_hh1, b_ih1, b_hh1,
        fc_w, fc_b, (float*)d_out);
}